// Round 13
// baseline (642.339 us; speedup 1.0000x reference)
//
#include <hip/hip_runtime.h>
#include <math.h>

#define AUX_SLOTS 1024
#define CAP 24576   // per-router ent segment capacity (expected count ~16384, sigma ~110)

// ---------------- fused gate + vl ----------------
// blocks 0..511: vl (normalized V-projections, NEW layout [R][L][H] -- scores
//   read row l as 64 contiguous floats -> s_load_x16 in gemm epilogue)
// blocks 512..2559: gate (logits, top-2, aux partials, direct scatter)
__global__ __launch_bounds__(256) void gate_vl_kernel(
    const float* __restrict__ llm, const float* __restrict__ Vw,
    const float* __restrict__ Vb, float* __restrict__ vl,
    const float* __restrict__ eh, const float* __restrict__ sr,
    const float* __restrict__ gw, const float* __restrict__ gb,
    int* __restrict__ ent, float* __restrict__ ewt,
    float* __restrict__ aux, int* __restrict__ cnt, int N)
{
    __shared__ float red[256];
    __shared__ int lcnt[8], lbase[8], lcur[8];
    __shared__ int   s_r01[32];
    __shared__ float s_w0[32], s_w1[32];
    int tid = threadIdx.x;

    if (blockIdx.x < 512) {
        // ---- vl part: 4 waves split the 384-dim dot (96 each), LDS reduce ----
        int b = blockIdx.x;          // b = r*64 + l
        int r = b >> 6, l = b & 63;
        int t = tid & 63, q = tid >> 6;
        const float* w  = Vw + ((size_t)r * 384 + q * 96) * 64 + t;
        const float* xr = llm + l * 384 + q * 96;
        float acc = 0.f;
#pragma unroll 4
        for (int d = 0; d < 96; ++d) acc += xr[d] * w[(size_t)d * 64];
        red[tid] = acc;
        __syncthreads();
        if (q == 0) {
            acc = red[t] + red[64 + t] + red[128 + t] + red[192 + t] + Vb[r * 64 + t];
            float ss = acc * acc;
#pragma unroll
            for (int m = 1; m < 64; m <<= 1) ss += __shfl_xor(ss, m);
            float inv = 1.0f / fmaxf(sqrtf(ss), 1e-12f);
            vl[(size_t)r * 4096 + l * 64 + t] = acc * inv;   // [r][l][h], coalesced
        }
        return;
    }

    // ---- gate part ----
    int bx = blockIdx.x - 512;
    if (tid < 8) { lcnt[tid] = 0; lcur[tid] = 0; }
    __syncthreads();
    int wave = tid >> 6, lane = tid & 63;
    int wgid = bx * 4 + wave;
    float gbr[8];
#pragma unroll
    for (int r = 0; r < 8; ++r) gbr[r] = gb[r];
    float aux_acc = 0.f;

    for (int rr = 0; rr < 8; ++rr) {
        int row = wgid * 8 + rr;
        const float4* pa = (const float4*)(eh + (size_t)row * 384);
        const float4* pb = (const float4*)(sr + (size_t)row * 384);
        float4 xv0 = pa[lane];
        const float4* p1 = (lane < 32) ? (pa + 64 + lane) : (pb + (lane - 32));
        float4 xv1 = *p1;
        float4 xv2 = pb[lane + 32];

        float lg[8];
#pragma unroll
        for (int r = 0; r < 8; ++r) lg[r] = 0.f;
        {
            const float* g0 = gw + (size_t)lane * 32;
            const float* g1 = gw + (size_t)(lane + 64) * 32;
            const float* g2 = gw + (size_t)(lane + 128) * 32;
            float xd;
#pragma unroll
            for (int dd = 0; dd < 4; ++dd) {
                xd = (dd == 0) ? xv0.x : (dd == 1) ? xv0.y : (dd == 2) ? xv0.z : xv0.w;
                float4 ga = *(const float4*)(g0 + dd * 8);
                float4 gbv = *(const float4*)(g0 + dd * 8 + 4);
                lg[0] += xd * ga.x;  lg[1] += xd * ga.y;
                lg[2] += xd * ga.z;  lg[3] += xd * ga.w;
                lg[4] += xd * gbv.x; lg[5] += xd * gbv.y;
                lg[6] += xd * gbv.z; lg[7] += xd * gbv.w;
            }
#pragma unroll
            for (int dd = 0; dd < 4; ++dd) {
                xd = (dd == 0) ? xv1.x : (dd == 1) ? xv1.y : (dd == 2) ? xv1.z : xv1.w;
                float4 ga = *(const float4*)(g1 + dd * 8);
                float4 gbv = *(const float4*)(g1 + dd * 8 + 4);
                lg[0] += xd * ga.x;  lg[1] += xd * ga.y;
                lg[2] += xd * ga.z;  lg[3] += xd * ga.w;
                lg[4] += xd * gbv.x; lg[5] += xd * gbv.y;
                lg[6] += xd * gbv.z; lg[7] += xd * gbv.w;
            }
#pragma unroll
            for (int dd = 0; dd < 4; ++dd) {
                xd = (dd == 0) ? xv2.x : (dd == 1) ? xv2.y : (dd == 2) ? xv2.z : xv2.w;
                float4 ga = *(const float4*)(g2 + dd * 8);
                float4 gbv = *(const float4*)(g2 + dd * 8 + 4);
                lg[0] += xd * ga.x;  lg[1] += xd * ga.y;
                lg[2] += xd * ga.z;  lg[3] += xd * ga.w;
                lg[4] += xd * gbv.x; lg[5] += xd * gbv.y;
                lg[6] += xd * gbv.z; lg[7] += xd * gbv.w;
            }
        }
#pragma unroll
        for (int m = 1; m < 64; m <<= 1) {
#pragma unroll
            for (int r = 0; r < 8; ++r) lg[r] += __shfl_xor(lg[r], m);
        }
#pragma unroll
        for (int r = 0; r < 8; ++r) lg[r] += gbr[r];

        float mx = lg[0];
#pragma unroll
        for (int r = 1; r < 8; ++r) mx = fmaxf(mx, lg[r]);
        float e8[8], se = 0.f;
#pragma unroll
        for (int r = 0; r < 8; ++r) { e8[r] = expf(lg[r] - mx); se += e8[r]; }

        int r0 = 0; float v0 = lg[0];
#pragma unroll
        for (int r = 1; r < 8; ++r) if (lg[r] > v0) { v0 = lg[r]; r0 = r; }
        int r1 = (r0 == 0) ? 1 : 0; float v1 = lg[r1];
#pragma unroll
        for (int r = 0; r < 8; ++r) if (r != r1 && r != r0 && lg[r] > v1) { v1 = lg[r]; r1 = r; }
        float z = expf(v1 - v0);
        float w0 = 1.f / (1.f + z), w1 = z / (1.f + z);

        if (lane == 0) {
            s_r01[wave * 8 + rr] = r0 | (r1 << 4);
            s_w0[wave * 8 + rr] = w0;
            s_w1[wave * 8 + rr] = w1;
            atomicAdd(&lcnt[r0], 1);
            atomicAdd(&lcnt[r1], 1);
        }
#pragma unroll
        for (int r2 = 0; r2 < 8; ++r2) {
            if (lane == r2) aux_acc += e8[r2] / se;
            if (lane - 8 == r2) aux_acc += (r2 == r0 || r2 == r1) ? 1.f : 0.f;
        }
    }
    if (lane < 16) atomicAdd(aux + ((size_t)(wgid & (AUX_SLOTS - 1)) * 16) + lane, aux_acc);
    __syncthreads();
    if (tid < 8) lbase[tid] = atomicAdd(&cnt[tid], lcnt[tid]);
    __syncthreads();
    if (tid < 32) {
        int ri = s_r01[tid];
        int row = bx * 32 + tid;
        int r0 = ri & 15, r1 = (ri >> 4) & 15;
        int p0 = lbase[r0] + atomicAdd(&lcur[r0], 1);
        ent[r0 * CAP + p0] = row << 1;       ewt[r0 * CAP + p0] = s_w0[tid];
        int p1 = lbase[r1] + atomicAdd(&lcur[r1], 1);
        ent[r1 * CAP + p1] = (row << 1) | 1; ewt[r1 * CAP + p1] = s_w1[tid];
    }
}

// ---------------- GEMM: scalar-B outer-product, lane = output row ----------------
// ROUND-13 structural change (the 292us 4x8 kernel was LDS-pipe-bound: 64 of
// 102 DS ops/chunk were b-reads with tx-only addresses). Here each lane owns
// ONE output row (acc[64]); b addresses are WAVE-UNIFORM -> compiler emits
// s_load into SGPRs; FMA is v_fmac v,s,v. DS ops/chunk drop 102 -> ~16
// (8 staging writes + 8 swizzled ds_read_b128 of the lane's own row).
// Epilogue fully lane-local: l2norm in-lane; scores read vl[r][l][0..63]
// (contiguous -> s_load_x16); softmax via private LDS strip (l ^ tid swizzle,
// conflict-free); no cross-lane shuffles at all.
__global__ __launch_bounds__(128, 1) void gemm_kernel(
    const float* __restrict__ eh, const float* __restrict__ sr,
    const float* __restrict__ Uw, const float* __restrict__ Ub,
    const float* __restrict__ vl, const int* __restrict__ ent,
    const float* __restrict__ ewt, const int* __restrict__ cnt,
    float* __restrict__ probs)
{
    int r = blockIdx.y;
    int count = cnt[r]; if (count > CAP) count = CAP;
    int tile = blockIdx.x;
    if (tile * 128 >= count) return;
    int base = r * CAP + tile * 128;

    __shared__ float lds[8192];      // 32 KB: first 16KB = x chunk; whole = score strips
    __shared__ int   sent[128];
    __shared__ float swt[128];
    float4* xs4 = (float4*)lds;

    int tid = threadIdx.x;           // 0..127; this thread's output row = tid
    {
        bool act = (tile * 128 + tid) < count;
        sent[tid] = act ? ent[base + tid] : -1;
        swt[tid]  = act ? ewt[base + tid] : 0.f;
    }
    __syncthreads();

    int tx = tid & 7, rg = tid >> 3;   // staging role: f4-col tx of rows rg+16p
    int rowst[8];
#pragma unroll
    for (int p = 0; p < 8; ++p) {
        int e = sent[rg + 16 * p];
        rowst[p] = (e < 0) ? 0 : (e >> 1);
    }
    int gmy = (tid ^ (tid >> 3)) & 7;  // own-row read swizzle

    float acc[64];
#pragma unroll
    for (int h = 0; h < 64; ++h) acc[h] = 0.f;

    const float* ubase = Uw + (size_t)r * 768 * 64;

    for (int c = 0; c < 24; ++c) {
        const float* xsrc = (c < 12) ? eh : sr;
        int dd0 = ((c < 12) ? c : c - 12) * 32;
        {   // stage x: 8 f4/thread, coalesced global, swizzled LDS slot
#pragma unroll
            for (int p = 0; p < 8; ++p) {
                int rw = rg + 16 * p;
                float4 v = ((const float4*)(xsrc + (size_t)rowst[p] * 384 + dd0))[tx];
                xs4[rw * 8 + (tx ^ ((rw ^ (rw >> 3)) & 7))] = v;
            }
        }
        __syncthreads();
        const float* up0 = ubase + (size_t)c * 32 * 64;
        for (int k8 = 0; k8 < 4; ++k8) {
            float4 xa = xs4[tid * 8 + ((2 * k8) ^ gmy)];
            float4 xb = xs4[tid * 8 + ((2 * k8 + 1) ^ gmy)];
            const float* up = up0 + k8 * 512;   // uniform -> s_load
#pragma unroll
            for (int kk = 0; kk < 8; ++kk) {
                float xk = (kk == 0) ? xa.x : (kk == 1) ? xa.y : (kk == 2) ? xa.z :
                           (kk == 3) ? xa.w : (kk == 4) ? xb.x : (kk == 5) ? xb.y :
                           (kk == 6) ? xb.z : xb.w;
#pragma unroll
                for (int h = 0; h < 64; ++h)
                    acc[h] = fmaf(up[kk * 64 + h], xk, acc[h]);
            }
        }
        __syncthreads();
    }

    // bias + l2norm, fully in-lane
    {
        const float* ubp = Ub + r * 64;   // uniform
        float ss = 0.f;
#pragma unroll
        for (int h = 0; h < 64; ++h) { acc[h] += ubp[h]; ss += acc[h] * acc[h]; }
        float inv = 1.0f / fmaxf(sqrtf(ss), 1e-12f);
#pragma unroll
        for (int h = 0; h < 64; ++h) acc[h] *= inv;
    }

    // scores pass 1: s_l = u . vl[l][*] (vl row contiguous -> s_load_x16),
    // park in private LDS strip (swizzle l^tid: conflict-free), track max
    const float* vp = vl + (size_t)r * 4096;
    int sw = tid & 63;
    float mx = -3.4e38f;
    for (int l = 0; l < 64; ++l) {
        const float* vpl = vp + l * 64;   // uniform
        float sl = 0.f;
#pragma unroll
        for (int h = 0; h < 64; ++h) sl = fmaf(vpl[h], acc[h], sl);
        lds[tid * 64 + (l ^ sw)] = sl;
        mx = fmaxf(mx, sl);
    }
    // pass 2: exp + sum (own strip only; no cross-thread sharing, no barrier)
    float ssum = 0.f;
    for (int l = 0; l < 64; ++l) {
        int a = tid * 64 + (l ^ sw);
        float e = expf(lds[a] - mx);
        ssum += e;
        lds[a] = e;
    }
    int ei = sent[tid];
    if (ei >= 0) {
        float wsc = swt[tid] / ssum;
        size_t bo = (size_t)(ei >> 1) * 128 + (size_t)(ei & 1) * 64;
#pragma unroll
        for (int l4 = 0; l4 < 16; ++l4) {
            float4 o;
            o.x = lds[tid * 64 + ((4 * l4 + 0) ^ sw)] * wsc;
            o.y = lds[tid * 64 + ((4 * l4 + 1) ^ sw)] * wsc;
            o.z = lds[tid * 64 + ((4 * l4 + 2) ^ sw)] * wsc;
            o.w = lds[tid * 64 + ((4 * l4 + 3) ^ sw)] * wsc;
            *(float4*)(probs + bo + 4 * l4) = o;
        }
    }
}

// ---------------- combine (+ aux in block 0) ----------------
__global__ __launch_bounds__(256) void combine_kernel(
    const float* __restrict__ probs, const float* __restrict__ rnd,
    const float* __restrict__ aux, float* __restrict__ out, int N)
{
    int w = threadIdx.x >> 6, lane = threadIdx.x & 63;
    int n = blockIdx.x * 4 + w;
    float p = probs[(size_t)n * 128 + lane] + probs[(size_t)n * 128 + 64 + lane];
    float rn = rnd[n];
    float c = 0.f; int sel = 0; bool found = false;
    for (int l = 0; l < 64; ++l) {
        float v = __shfl(p, l);
        c += v;
        if (!found && c > rn) { sel = l; found = true; }
    }
    float pv = __shfl(p, sel);
    if (lane == 0) {
        out[n] = (float)sel;
        out[N + n] = logf(pv);
    }

    if (blockIdx.x == 0) {
        __shared__ float red[256];
        int tid = threadIdx.x;
        int j = tid & 15, s0 = tid >> 4;
        float acc = 0.f;
        for (int s = s0; s < AUX_SLOTS; s += 16) acc += aux[s * 16 + j];
        red[tid] = acc;
        __syncthreads();
        if (tid < 16) {
            float a = 0.f;
            for (int g = 0; g < 16; ++g) a += red[g * 16 + tid];
            red[tid] = a;
        }
        __syncthreads();
        if (tid == 0) {
            float invN = 1.f / (float)N;
            float t = 0.f;
            for (int r2 = 0; r2 < 8; ++r2) t += (red[r2] * invN) * (red[8 + r2] * invN);
            out[2 * N] = 8.0f * 0.05f * t;
        }
    }
}

extern "C" void kernel_launch(void* const* d_in, const int* in_sizes, int n_in,
                              void* d_out, int out_size, void* d_ws, size_t ws_size,
                              hipStream_t stream) {
    const float* eh  = (const float*)d_in[0];
    const float* sr  = (const float*)d_in[1];
    const float* llm = (const float*)d_in[2];
    const float* rnd = (const float*)d_in[3];
    const float* gw  = (const float*)d_in[4];
    const float* gb  = (const float*)d_in[5];
    const float* Uw  = (const float*)d_in[6];
    const float* Ub  = (const float*)d_in[7];
    const float* Vw  = (const float*)d_in[8];
    const float* Vb  = (const float*)d_in[9];
    int N = in_sizes[0] / 384;

    float* vl    = (float*)d_ws;              // 32768 f
    float* aux   = vl + 32768;                // 16384 f
    int*   cnt   = (int*)(aux + 16384);       // 8 i
    int*   ent   = cnt + 8;                   // 8*CAP i
    float* ewt   = (float*)(ent + 8 * CAP);   // 8*CAP f
    float* probs = ewt + 8 * CAP;             // N*128 f

    hipMemsetAsync(aux, 0, 16384 * sizeof(float) + 8 * sizeof(int), stream);
    gate_vl_kernel<<<512 + N / 32, 256, 0, stream>>>(llm, Vw, Vb, vl, eh, sr, gw, gb,
                                                     ent, ewt, aux, cnt, N);
    gemm_kernel<<<dim3(CAP / 128, 8), 128, 0, stream>>>(eh, sr, Uw, Ub, vl, ent, ewt,
                                                        cnt, probs);
    combine_kernel<<<N / 4, 256, 0, stream>>>(probs, rnd, aux, (float*)d_out, N);
}

// Round 15
// 412.600 us; speedup vs baseline: 1.5568x; 1.5568x over previous
//
#include <hip/hip_runtime.h>
#include <math.h>

#define AUX_SLOTS 1024
#define CAP 24576   // per-router ent segment capacity (expected count ~16384, sigma ~110)

// ---------------- fused gate + vl ----------------
// blocks 0..511: vl (normalized V-projections, layout [R][H][L])
// blocks 512..2559: gate (logits, top-2, aux partials, direct scatter)
// vl overlaps gate's execution; one launch + one gap saved vs separate kernels.
// NOTE (r14): cooperative mega-kernel merge HANGS under the harness's graph
// capture (hipLaunchCooperativeKernel times out, no error code) -- do not retry.
__global__ __launch_bounds__(256) void gate_vl_kernel(
    const float* __restrict__ llm, const float* __restrict__ Vw,
    const float* __restrict__ Vb, float* __restrict__ vl,
    const float* __restrict__ eh, const float* __restrict__ sr,
    const float* __restrict__ gw, const float* __restrict__ gb,
    int* __restrict__ ent, float* __restrict__ ewt,
    float* __restrict__ aux, int* __restrict__ cnt, int N)
{
    __shared__ float red[256];
    __shared__ int lcnt[8], lbase[8], lcur[8];
    __shared__ int   s_r01[32];
    __shared__ float s_w0[32], s_w1[32];
    int tid = threadIdx.x;

    if (blockIdx.x < 512) {
        // ---- vl part: 4 waves split the 384-dim dot (96 each), LDS reduce ----
        int b = blockIdx.x;          // b = r*64 + l
        int r = b >> 6, l = b & 63;
        int t = tid & 63, q = tid >> 6;
        const float* w  = Vw + ((size_t)r * 384 + q * 96) * 64 + t;
        const float* xr = llm + l * 384 + q * 96;
        float acc = 0.f;
#pragma unroll 4
        for (int d = 0; d < 96; ++d) acc += xr[d] * w[(size_t)d * 64];
        red[tid] = acc;
        __syncthreads();
        if (q == 0) {
            acc = red[t] + red[64 + t] + red[128 + t] + red[192 + t] + Vb[r * 64 + t];
            float ss = acc * acc;
#pragma unroll
            for (int m = 1; m < 64; m <<= 1) ss += __shfl_xor(ss, m);
            float inv = 1.0f / fmaxf(sqrtf(ss), 1e-12f);
            vl[((size_t)r * 64 + t) * 64 + l] = acc * inv;   // [r][h][l]
        }
        return;
    }

    // ---- gate part ----
    int bx = blockIdx.x - 512;
    if (tid < 8) { lcnt[tid] = 0; lcur[tid] = 0; }
    __syncthreads();
    int wave = tid >> 6, lane = tid & 63;
    int wgid = bx * 4 + wave;
    float gbr[8];
#pragma unroll
    for (int r = 0; r < 8; ++r) gbr[r] = gb[r];
    float aux_acc = 0.f;

    for (int rr = 0; rr < 8; ++rr) {
        int row = wgid * 8 + rr;
        const float4* pa = (const float4*)(eh + (size_t)row * 384);
        const float4* pb = (const float4*)(sr + (size_t)row * 384);
        float4 xv0 = pa[lane];
        const float4* p1 = (lane < 32) ? (pa + 64 + lane) : (pb + (lane - 32));
        float4 xv1 = *p1;
        float4 xv2 = pb[lane + 32];

        float lg[8];
#pragma unroll
        for (int r = 0; r < 8; ++r) lg[r] = 0.f;
        {
            // gw loads vectorized: 24 float4 loads/row instead of 96 scalar (G13)
            const float* g0 = gw + (size_t)lane * 32;
            const float* g1 = gw + (size_t)(lane + 64) * 32;
            const float* g2 = gw + (size_t)(lane + 128) * 32;
            float xd;
#pragma unroll
            for (int dd = 0; dd < 4; ++dd) {
                xd = (dd == 0) ? xv0.x : (dd == 1) ? xv0.y : (dd == 2) ? xv0.z : xv0.w;
                float4 ga = *(const float4*)(g0 + dd * 8);
                float4 gbv = *(const float4*)(g0 + dd * 8 + 4);
                lg[0] += xd * ga.x;  lg[1] += xd * ga.y;
                lg[2] += xd * ga.z;  lg[3] += xd * ga.w;
                lg[4] += xd * gbv.x; lg[5] += xd * gbv.y;
                lg[6] += xd * gbv.z; lg[7] += xd * gbv.w;
            }
#pragma unroll
            for (int dd = 0; dd < 4; ++dd) {
                xd = (dd == 0) ? xv1.x : (dd == 1) ? xv1.y : (dd == 2) ? xv1.z : xv1.w;
                float4 ga = *(const float4*)(g1 + dd * 8);
                float4 gbv = *(const float4*)(g1 + dd * 8 + 4);
                lg[0] += xd * ga.x;  lg[1] += xd * ga.y;
                lg[2] += xd * ga.z;  lg[3] += xd * ga.w;
                lg[4] += xd * gbv.x; lg[5] += xd * gbv.y;
                lg[6] += xd * gbv.z; lg[7] += xd * gbv.w;
            }
#pragma unroll
            for (int dd = 0; dd < 4; ++dd) {
                xd = (dd == 0) ? xv2.x : (dd == 1) ? xv2.y : (dd == 2) ? xv2.z : xv2.w;
                float4 ga = *(const float4*)(g2 + dd * 8);
                float4 gbv = *(const float4*)(g2 + dd * 8 + 4);
                lg[0] += xd * ga.x;  lg[1] += xd * ga.y;
                lg[2] += xd * ga.z;  lg[3] += xd * ga.w;
                lg[4] += xd * gbv.x; lg[5] += xd * gbv.y;
                lg[6] += xd * gbv.z; lg[7] += xd * gbv.w;
            }
        }
#pragma unroll
        for (int m = 1; m < 64; m <<= 1) {
#pragma unroll
            for (int r = 0; r < 8; ++r) lg[r] += __shfl_xor(lg[r], m);
        }
#pragma unroll
        for (int r = 0; r < 8; ++r) lg[r] += gbr[r];

        float mx = lg[0];
#pragma unroll
        for (int r = 1; r < 8; ++r) mx = fmaxf(mx, lg[r]);
        float e8[8], se = 0.f;
#pragma unroll
        for (int r = 0; r < 8; ++r) { e8[r] = expf(lg[r] - mx); se += e8[r]; }

        int r0 = 0; float v0 = lg[0];
#pragma unroll
        for (int r = 1; r < 8; ++r) if (lg[r] > v0) { v0 = lg[r]; r0 = r; }
        int r1 = (r0 == 0) ? 1 : 0; float v1 = lg[r1];
#pragma unroll
        for (int r = 0; r < 8; ++r) if (r != r1 && r != r0 && lg[r] > v1) { v1 = lg[r]; r1 = r; }
        float z = expf(v1 - v0);
        float w0 = 1.f / (1.f + z), w1 = z / (1.f + z);

        if (lane == 0) {
            s_r01[wave * 8 + rr] = r0 | (r1 << 4);
            s_w0[wave * 8 + rr] = w0;
            s_w1[wave * 8 + rr] = w1;
            atomicAdd(&lcnt[r0], 1);
            atomicAdd(&lcnt[r1], 1);
        }
#pragma unroll
        for (int r2 = 0; r2 < 8; ++r2) {
            if (lane == r2) aux_acc += e8[r2] / se;
            if (lane - 8 == r2) aux_acc += (r2 == r0 || r2 == r1) ? 1.f : 0.f;
        }
    }
    if (lane < 16) atomicAdd(aux + ((size_t)(wgid & (AUX_SLOTS - 1)) * 16) + lane, aux_acc);
    __syncthreads();
    if (tid < 8) lbase[tid] = atomicAdd(&cnt[tid], lcnt[tid]);
    __syncthreads();
    if (tid < 32) {   // one thread per row of this block: write both entries
        int ri = s_r01[tid];
        int row = bx * 32 + tid;
        int r0 = ri & 15, r1 = (ri >> 4) & 15;
        int p0 = lbase[r0] + atomicAdd(&lcur[r0], 1);
        ent[r0 * CAP + p0] = row << 1;       ewt[r0 * CAP + p0] = s_w0[tid];
        int p1 = lbase[r1] + atomicAdd(&lcur[r1], 1);
        ent[r1 * CAP + p1] = (row << 1) | 1; ewt[r1 * CAP + p1] = s_w1[tid];
    }
}

// ---------------- fused projection GEMM + l2norm + scores + softmax ----------------
// EXACT round-9 kernel (292us, proven optimum across 10 structural variants:
// bigger/smaller tiles, 8x8 micro-tile, K-split, 1-wave blocks, DMA staging,
// 3x register-prefetch, scalar-B outer-product -- all regressed). LDS-op
// accounting: ~197us LDS-pipe busy of 292 = 67% pipe utilization; the gap is
// barrier-coupled staging latency the HIP compiler's vmcnt(0) drain exposes
// (documented m97-structure ceiling; reg-prefetch spills are allocator-
// uncontrollable at this occupancy: 3/3 attempts spilled).
__global__ __launch_bounds__(256, 3) void gemm_kernel(
    const float* __restrict__ eh, const float* __restrict__ sr,
    const float* __restrict__ Uw, const float* __restrict__ Ub,
    const float* __restrict__ vl, const int* __restrict__ ent,
    const float* __restrict__ ewt, const int* __restrict__ cnt,
    float* __restrict__ probs)
{
    int r = blockIdx.y;
    int count = cnt[r]; if (count > CAP) count = CAP;
    int tile = blockIdx.x;
    if (tile * 128 >= count) return;
    int base = r * CAP + tile * 128;

    __shared__ float xs[128 * 32];   // 16 KB, f4-swizzled [row][k4 ^ ((row>>2)&7)]
    __shared__ float us[32 * 64];    // 8 KB, U chunk [k][h]
    __shared__ int   sent[128];
    __shared__ float swt[128];

    int tid = threadIdx.x;
    int tx = tid & 7, ty = tid >> 3;   // ty 0..31, rows 4ty..4ty+3; h 8tx..8tx+7
    float4* xs4 = (float4*)xs;
    float4* us4 = (float4*)us;

    if (tid < 128) {
        bool act = (tile * 128 + tid) < count;
        sent[tid] = act ? ent[base + tid] : -1;
        swt[tid]  = act ? ewt[base + tid] : 0.f;
    }
    __syncthreads();

    // cache this thread's staging row ids (rloc = ty + 32p)
    int rowp[4];
#pragma unroll
    for (int p = 0; p < 4; ++p) {
        int e = sent[ty + 32 * p];
        rowp[p] = (e < 0) ? 0 : (e >> 1);
    }

    float acc[4][8];
#pragma unroll
    for (int i = 0; i < 4; ++i)
#pragma unroll
        for (int j = 0; j < 8; ++j) acc[i][j] = 0.f;

    for (int c = 0; c < 24; ++c) {
        const float* xsrc = (c < 12) ? eh : sr;
        int dd0 = ((c < 12) ? c : c - 12) * 32;
        {   // stage x: 4 f4 per thread, 128B contiguous per row
#pragma unroll
            for (int p = 0; p < 4; ++p) {
                int rloc = ty + 32 * p;
                float4 v = ((const float4*)(xsrc + (size_t)rowp[p] * 384 + dd0))[tx];
                xs4[rloc * 8 + (tx ^ ((rloc >> 2) & 7))] = v;
            }
        }
        {   // stage U chunk [32k][64h], linear
            const float4* pu = (const float4*)(Uw + ((size_t)r * 768 + (size_t)c * 32) * 64);
            us4[tid] = pu[tid];
            us4[tid + 256] = pu[tid + 256];
        }
        __syncthreads();
#pragma unroll
        for (int k4 = 0; k4 < 8; ++k4) {
            float4 a[4];
#pragma unroll
            for (int i = 0; i < 4; ++i)
                a[i] = xs4[(4 * ty + i) * 8 + (k4 ^ (ty & 7))];
#pragma unroll
            for (int j = 0; j < 4; ++j) {
                float4 b0 = us4[(k4 * 4 + j) * 16 + tx * 2];
                float4 b1 = us4[(k4 * 4 + j) * 16 + tx * 2 + 1];
#pragma unroll
                for (int i = 0; i < 4; ++i) {
                    float av = (j == 0) ? a[i].x : (j == 1) ? a[i].y : (j == 2) ? a[i].z : a[i].w;
                    acc[i][0] += av * b0.x; acc[i][1] += av * b0.y;
                    acc[i][2] += av * b0.z; acc[i][3] += av * b0.w;
                    acc[i][4] += av * b1.x; acc[i][5] += av * b1.y;
                    acc[i][6] += av * b1.z; acc[i][7] += av * b1.w;
                }
            }
        }
        __syncthreads();
    }

    // bias + l2-normalize rows (partial over tx, xor-shfl 1,2,4)
    float ub[8];
#pragma unroll
    for (int j = 0; j < 8; ++j) ub[j] = Ub[r * 64 + 8 * tx + j];
#pragma unroll
    for (int i = 0; i < 4; ++i) {
        float ss = 0.f;
#pragma unroll
        for (int j = 0; j < 8; ++j) { acc[i][j] += ub[j]; ss += acc[i][j] * acc[i][j]; }
#pragma unroll
        for (int m = 1; m <= 4; m <<= 1) ss += __shfl_xor(ss, m);
        float inv = 1.0f / fmaxf(sqrtf(ss), 1e-12f);
#pragma unroll
        for (int j = 0; j < 8; ++j) acc[i][j] *= inv;
    }

    // stage vl[r] (16 KB) into xs, swizzled [h][l4 ^ ((h>>3)&7)]
    {
        const float4* pv = (const float4*)(vl + (size_t)r * 4096);
#pragma unroll
        for (int p = 0; p < 4; ++p) {
            int idx = tid + p * 256;
            int h = idx >> 4, l4 = idx & 15;
            xs4[h * 16 + (l4 ^ ((h >> 3) & 7))] = pv[idx];
        }
    }
    __syncthreads();

    // scores + softmax + store, in two 2-row halves (register pressure)
#pragma unroll
    for (int ih = 0; ih < 4; ih += 2) {
        float sc[2][8];
        for (int lc = 0; lc < 8; ++lc) {
            float part[2][8];
#pragma unroll
            for (int i = 0; i < 2; ++i)
#pragma unroll
                for (int j = 0; j < 8; ++j) part[i][j] = 0.f;
#pragma unroll
            for (int j = 0; j < 8; ++j) {
                int h = 8 * tx + j;
                float4 v0 = xs4[h * 16 + ((2 * lc) ^ tx)];
                float4 v1 = xs4[h * 16 + ((2 * lc + 1) ^ tx)];
#pragma unroll
                for (int i = 0; i < 2; ++i) {
                    float uv = acc[ih + i][j];
                    part[i][0] += uv * v0.x; part[i][1] += uv * v0.y;
                    part[i][2] += uv * v0.z; part[i][3] += uv * v0.w;
                    part[i][4] += uv * v1.x; part[i][5] += uv * v1.y;
                    part[i][6] += uv * v1.z; part[i][7] += uv * v1.w;
                }
            }
#pragma unroll
            for (int m = 1; m <= 4; m <<= 1)
#pragma unroll
                for (int i = 0; i < 2; ++i)
#pragma unroll
                    for (int j = 0; j < 8; ++j) part[i][j] += __shfl_xor(part[i][j], m);
            if (tx == lc) {
#pragma unroll
                for (int i = 0; i < 2; ++i)
#pragma unroll
                    for (int j = 0; j < 8; ++j) sc[i][j] = part[i][j];
            }
        }
#pragma unroll
        for (int i = 0; i < 2; ++i) {
            float mx = sc[i][0];
#pragma unroll
            for (int j = 1; j < 8; ++j) mx = fmaxf(mx, sc[i][j]);
#pragma unroll
            for (int m = 1; m <= 4; m <<= 1) mx = fmaxf(mx, __shfl_xor(mx, m));
            float e[8], ssum = 0.f;
#pragma unroll
            for (int j = 0; j < 8; ++j) { e[j] = expf(sc[i][j] - mx); ssum += e[j]; }
#pragma unroll
            for (int m = 1; m <= 4; m <<= 1) ssum += __shfl_xor(ssum, m);
            int rloc = 4 * ty + ih + i;
            int ei = sent[rloc];
            if (ei >= 0) {
                float w = swt[rloc];
                float4 o0, o1;
                o0.x = (e[0] / ssum) * w; o0.y = (e[1] / ssum) * w;
                o0.z = (e[2] / ssum) * w; o0.w = (e[3] / ssum) * w;
                o1.x = (e[4] / ssum) * w; o1.y = (e[5] / ssum) * w;
                o1.z = (e[6] / ssum) * w; o1.w = (e[7] / ssum) * w;
                size_t bo = (size_t)(ei >> 1) * 128 + (size_t)(ei & 1) * 64 + 8 * tx;
                *(float4*)(probs + bo) = o0;
                *(float4*)(probs + bo + 4) = o1;
            }
        }
    }
}

// ---------------- combine (+ aux in block 0) ----------------
__global__ __launch_bounds__(256) void combine_kernel(
    const float* __restrict__ probs, const float* __restrict__ rnd,
    const float* __restrict__ aux, float* __restrict__ out, int N)
{
    int w = threadIdx.x >> 6, lane = threadIdx.x & 63;
    int n = blockIdx.x * 4 + w;
    float p = probs[(size_t)n * 128 + lane] + probs[(size_t)n * 128 + 64 + lane];
    float rn = rnd[n];
    float c = 0.f; int sel = 0; bool found = false;
    for (int l = 0; l < 64; ++l) {
        float v = __shfl(p, l);
        c += v;
        if (!found && c > rn) { sel = l; found = true; }
    }
    float pv = __shfl(p, sel);
    if (lane == 0) {
        out[n] = (float)sel;
        out[N + n] = logf(pv);
    }

    if (blockIdx.x == 0) {   // aux reduction rides along (saves a dispatch)
        __shared__ float red[256];
        int tid = threadIdx.x;
        int j = tid & 15, s0 = tid >> 4;
        float acc = 0.f;
        for (int s = s0; s < AUX_SLOTS; s += 16) acc += aux[s * 16 + j];
        red[tid] = acc;
        __syncthreads();
        if (tid < 16) {
            float a = 0.f;
            for (int g = 0; g < 16; ++g) a += red[g * 16 + tid];
            red[tid] = a;
        }
        __syncthreads();
        if (tid == 0) {
            float invN = 1.f / (float)N;
            float t = 0.f;
            for (int r2 = 0; r2 < 8; ++r2) t += (red[r2] * invN) * (red[8 + r2] * invN);
            out[2 * N] = 8.0f * 0.05f * t;
        }
    }
}

extern "C" void kernel_launch(void* const* d_in, const int* in_sizes, int n_in,
                              void* d_out, int out_size, void* d_ws, size_t ws_size,
                              hipStream_t stream) {
    const float* eh  = (const float*)d_in[0];
    const float* sr  = (const float*)d_in[1];
    const float* llm = (const float*)d_in[2];
    const float* rnd = (const float*)d_in[3];
    const float* gw  = (const float*)d_in[4];
    const float* gb  = (const float*)d_in[5];
    const float* Uw  = (const float*)d_in[6];
    const float* Ub  = (const float*)d_in[7];
    const float* Vw  = (const float*)d_in[8];
    const float* Vb  = (const float*)d_in[9];
    int N = in_sizes[0] / 384;

    float* vl    = (float*)d_ws;              // 32768 f
    float* aux   = vl + 32768;                // 16384 f
    int*   cnt   = (int*)(aux + 16384);       // 8 i
    int*   ent   = cnt + 8;                   // 8*CAP i
    float* ewt   = (float*)(ent + 8 * CAP);   // 8*CAP f
    float* probs = ewt + 8 * CAP;             // N*128 f

    hipMemsetAsync(aux, 0, 16384 * sizeof(float) + 8 * sizeof(int), stream);
    gate_vl_kernel<<<512 + N / 32, 256, 0, stream>>>(llm, Vw, Vb, vl, eh, sr, gw, gb,
                                                     ent, ewt, aux, cnt, N);
    gemm_kernel<<<dim3(CAP / 128, 8), 256, 0, stream>>>(eh, sr, Uw, Ub, vl, ent, ewt,
                                                        cnt, probs);
    combine_kernel<<<N / 4, 256, 0, stream>>>(probs, rnd, aux, (float*)d_out, N);
}